// Round 4
// baseline (2524.433 us; speedup 1.0000x reference)
//
#include <hip/hip_runtime.h>
#include <cstdint>

// Problem constants
#define BATCH 32
#define CIN   64
#define CEXP  256
#define CSE   64
#define COUT  64
#define HH    112
#define WW    112
#define HWP   (112*112)   // 12544
#define TILE  14          // interior tile
#define THL   16          // tile + 3x3 halo = exactly 256 pixels = 1/thread
#define NPIX  (THL*THL)   // 256
#define NTIL  8           // 112/14
#define CHUNK 32

// -------------------------------------------------------------------------
// Kernel 1: fused expand 1x1 conv + ReLU + depthwise 3x3 + bias + ReLU.
// STORE=1: writes h2 chunk [nb][256][112][112] (local batch index) and
// per-(b,channel) partial sums. STORE=0: sums only (tier-B first pass).
// Block = (local batch, 14x14 tile), 256 threads = one 16x16 halo pixel each.
// -------------------------------------------------------------------------
template <bool STORE>
__global__ __launch_bounds__(256) void k1_expand_dw(
    const float* __restrict__ x, const float* __restrict__ w1,
    const float* __restrict__ w2, const float* __restrict__ b1,
    const float* __restrict__ b2, float* __restrict__ h2,
    float* __restrict__ sums, int b0)
{
    __shared__ __align__(16) float h1s[CHUNK][NPIX];   // 32 KiB

    const int tid = threadIdx.x;
    const int bl  = blockIdx.y;          // local batch (h2 index)
    const int bg  = b0 + bl;             // global batch (x / sums index)
    const int tile = blockIdx.x;
    const int ty = tile >> 3, tx = tile & 7;
    const int h0 = ty * TILE - 1, w0 = tx * TILE - 1;

    // halo pixel owned by this thread
    const int hy = tid >> 4, hx = tid & 15;
    const int hh = h0 + hy, ww = w0 + hx;
    const bool in = ((unsigned)hh < HH) && ((unsigned)ww < WW);

    float xr[CIN];
    {
        const float* xb = x + (size_t)bg * CIN * HWP;
        const int off = in ? (hh * WW + ww) : 0;
        #pragma unroll
        for (int c = 0; c < CIN; ++c) xr[c] = xb[c * HWP + off];
        if (!in) {
            #pragma unroll
            for (int c = 0; c < CIN; ++c) xr[c] = 0.f;
        }
    }

    // interior output pixel for dw phase; clamp indices for inactive threads
    const bool active = (tid < TILE * TILE);
    const int  y_  = tid / TILE;
    const int  y   = active ? y_ : 0;
    const int  xc  = active ? (tid - y_ * TILE) : 0;
    const size_t h2base = (size_t)bl * CEXP * HWP;

    for (int chunk = 0; chunk < CEXP / CHUNK; ++chunk) {
        const int oc0 = chunk * CHUNK;

        // ---- expand conv into LDS h1 chunk (1 pixel/thread) ----
        #pragma unroll 2
        for (int ocb = 0; ocb < CHUNK; ++ocb) {
            const int oc = oc0 + ocb;
            const float* __restrict__ wr = w1 + oc * CIN;   // uniform -> s_load
            // dual dependent chains: issue-bound instead of latency-bound
            float a0 = b1[oc], a1 = 0.f;
            #pragma unroll
            for (int c = 0; c < CIN; c += 2) {
                a0 = fmaf(xr[c],     wr[c],     a0);
                a1 = fmaf(xr[c + 1], wr[c + 1], a1);
            }
            const float a = a0 + a1;
            h1s[ocb][tid] = in ? fmaxf(a, 0.f) : 0.f;   // zero-pad outside image
        }
        __syncthreads();

        // ---- depthwise 3x3 + bias + ReLU + store + channel sums ----
        for (int i = 0; i < CHUNK; ++i) {
            const int oc = oc0 + i;
            const float* __restrict__ w2r = w2 + oc * 9;    // uniform -> s_load
            float v = b2[oc];
            #pragma unroll
            for (int ky = 0; ky < 3; ++ky)
                #pragma unroll
                for (int kx = 0; kx < 3; ++kx)
                    v = fmaf(h1s[i][(y + ky) * THL + (xc + kx)], w2r[ky * 3 + kx], v);
            v = fmaxf(v, 0.f);
            v = active ? v : 0.f;
            if (STORE && active)
                h2[h2base + (size_t)oc * HWP + (ty * TILE + y) * WW + (tx * TILE + xc)] = v;

            float s = v;
            #pragma unroll
            for (int off = 32; off > 0; off >>= 1) s += __shfl_xor(s, off, 64);
            if ((tid & 63) == 0) atomicAdd(&sums[bg * CEXP + oc], s);
        }
        __syncthreads();
    }
}

// -------------------------------------------------------------------------
// Kernel 2: SE tail. mean -> FC(64)+ReLU -> FC(256)+sigmoid, pre-fold into
// w5se[b][e][o] = w5[o][e] * se2[b][e]. One block per batch in [b0, b0+nb).
// -------------------------------------------------------------------------
__global__ __launch_bounds__(256) void k2_se(
    const float* __restrict__ sums, const float* __restrict__ w3,
    const float* __restrict__ w4, const float* __restrict__ w5,
    const float* __restrict__ b3, const float* __restrict__ b4,
    float* __restrict__ w5se, int b0)
{
    __shared__ float mean_s[CEXP];
    __shared__ float se1_s[CSE];
    __shared__ float se2_s[CEXP];

    const int tid = threadIdx.x;
    const int b   = b0 + blockIdx.x;

    mean_s[tid] = sums[b * CEXP + tid] * (1.f / (float)HWP);
    __syncthreads();

    if (tid < CSE) {
        float a0 = b3[tid], a1 = 0.f;
        for (int e = 0; e < CEXP; e += 2) {
            a0 = fmaf(mean_s[e],     w3[tid * CEXP + e],     a0);
            a1 = fmaf(mean_s[e + 1], w3[tid * CEXP + e + 1], a1);
        }
        se1_s[tid] = fmaxf(a0 + a1, 0.f);
    }
    __syncthreads();

    {
        float a0 = b4[tid], a1 = 0.f;
        #pragma unroll
        for (int s = 0; s < CSE; s += 2) {
            a0 = fmaf(se1_s[s],     w4[tid * CSE + s],     a0);
            a1 = fmaf(se1_s[s + 1], w4[tid * CSE + s + 1], a1);
        }
        const float acc = a0 + a1;
        se2_s[tid] = 1.f / (1.f + expf(-acc));
    }
    __syncthreads();

    for (int i = tid; i < CEXP * COUT; i += 256) {
        const int e = i >> 6, o = i & 63;
        w5se[(size_t)b * CEXP * COUT + i] = w5[o * CEXP + e] * se2_s[e];
    }
}

// -------------------------------------------------------------------------
// Kernel 3 (tier A): project 1x1 from stored h2 (local batch index).
// Thread = one pixel, 64 accumulators (64 parallel FMA chains -> issue-
// bound); w5se rows via uniform scalar loads.
// -------------------------------------------------------------------------
__global__ __launch_bounds__(256) void k3_project(
    const float* __restrict__ h2, const float* __restrict__ w5se,
    const float* __restrict__ b5, float* __restrict__ out, int b0)
{
    const int tid = threadIdx.x;
    const int bl  = blockIdx.y;
    const int bg  = b0 + bl;
    const int p   = blockIdx.x * 256 + tid;

    const float* __restrict__ hp = h2 + (size_t)bl * CEXP * HWP + p;
    const float* __restrict__ wp = w5se + (size_t)bg * CEXP * COUT;

    float acc[COUT];
    #pragma unroll
    for (int o = 0; o < COUT; ++o) acc[o] = b5[o];

    #pragma unroll 4
    for (int e = 0; e < CEXP; ++e) {
        const float hv = hp[(size_t)e * HWP];
        const float* __restrict__ wr = wp + e * COUT;   // uniform -> s_load
        #pragma unroll
        for (int o = 0; o < COUT; ++o)
            acc[o] = fmaf(hv, wr[o], acc[o]);
    }

    float* __restrict__ op = out + (size_t)bg * COUT * HWP + p;
    #pragma unroll
    for (int o = 0; o < COUT; ++o) op[(size_t)o * HWP] = acc[o];
}

// -------------------------------------------------------------------------
// Kernel 3 (tier B): recompute expand+dw per tile, project in registers.
// No h2 materialization at all. acc[64] per interior pixel.
// -------------------------------------------------------------------------
__global__ __launch_bounds__(256) void k3_fused(
    const float* __restrict__ x, const float* __restrict__ w1,
    const float* __restrict__ w2, const float* __restrict__ b1,
    const float* __restrict__ b2, const float* __restrict__ w5se,
    const float* __restrict__ b5, float* __restrict__ out)
{
    __shared__ __align__(16) float h1s[CHUNK][NPIX];   // 32 KiB

    const int tid = threadIdx.x;
    const int b   = blockIdx.y;
    const int tile = blockIdx.x;
    const int ty = tile >> 3, tx = tile & 7;
    const int h0 = ty * TILE - 1, w0 = tx * TILE - 1;

    const int hy = tid >> 4, hx = tid & 15;
    const int hh = h0 + hy, ww = w0 + hx;
    const bool in = ((unsigned)hh < HH) && ((unsigned)ww < WW);

    float xr[CIN];
    {
        const float* xb = x + (size_t)b * CIN * HWP;
        const int off = in ? (hh * WW + ww) : 0;
        #pragma unroll
        for (int c = 0; c < CIN; ++c) xr[c] = xb[c * HWP + off];
        if (!in) {
            #pragma unroll
            for (int c = 0; c < CIN; ++c) xr[c] = 0.f;
        }
    }

    const bool active = (tid < TILE * TILE);
    const int  y_  = tid / TILE;
    const int  y   = active ? y_ : 0;
    const int  xc  = active ? (tid - y_ * TILE) : 0;

    const float* __restrict__ wp = w5se + (size_t)b * CEXP * COUT;

    float acc[COUT];
    #pragma unroll
    for (int o = 0; o < COUT; ++o) acc[o] = b5[o];

    for (int chunk = 0; chunk < CEXP / CHUNK; ++chunk) {
        const int oc0 = chunk * CHUNK;

        #pragma unroll 2
        for (int ocb = 0; ocb < CHUNK; ++ocb) {
            const int oc = oc0 + ocb;
            const float* __restrict__ wr = w1 + oc * CIN;
            float a0 = b1[oc], a1 = 0.f;
            #pragma unroll
            for (int c = 0; c < CIN; c += 2) {
                a0 = fmaf(xr[c],     wr[c],     a0);
                a1 = fmaf(xr[c + 1], wr[c + 1], a1);
            }
            const float a = a0 + a1;
            h1s[ocb][tid] = in ? fmaxf(a, 0.f) : 0.f;
        }
        __syncthreads();

        for (int i = 0; i < CHUNK; ++i) {
            const int oc = oc0 + i;
            const float* __restrict__ w2r = w2 + oc * 9;
            float v = b2[oc];
            #pragma unroll
            for (int ky = 0; ky < 3; ++ky)
                #pragma unroll
                for (int kx = 0; kx < 3; ++kx)
                    v = fmaf(h1s[i][(y + ky) * THL + (xc + kx)], w2r[ky * 3 + kx], v);
            v = fmaxf(v, 0.f);
            const float* __restrict__ wr = wp + oc * COUT;  // uniform -> s_load
            #pragma unroll
            for (int o = 0; o < COUT; ++o)
                acc[o] = fmaf(v, wr[o], acc[o]);
        }
        __syncthreads();
    }

    if (active) {
        const int p = (ty * TILE + y) * WW + (tx * TILE + xc);
        float* __restrict__ op = out + (size_t)b * COUT * HWP + p;
        #pragma unroll
        for (int o = 0; o < COUT; ++o) op[(size_t)o * HWP] = acc[o];
    }
}

// -------------------------------------------------------------------------
extern "C" void kernel_launch(void* const* d_in, const int* in_sizes, int n_in,
                              void* d_out, int out_size, void* d_ws, size_t ws_size,
                              hipStream_t stream)
{
    const float* x  = (const float*)d_in[0];
    const float* w1 = (const float*)d_in[1];
    const float* w2 = (const float*)d_in[2];
    const float* w3 = (const float*)d_in[3];
    const float* w4 = (const float*)d_in[4];
    const float* w5 = (const float*)d_in[5];
    const float* b1 = (const float*)d_in[6];
    const float* b2 = (const float*)d_in[7];
    const float* b3 = (const float*)d_in[8];
    const float* b4 = (const float*)d_in[9];
    const float* b5 = (const float*)d_in[10];
    float* out = (float*)d_out;

    // workspace layout: sums (32 KB) | w5se (2 MB) | h2 (whatever fits)
    const size_t sums_elems = (size_t)BATCH * CEXP;              // 8192
    const size_t w5se_elems = (size_t)BATCH * CEXP * COUT;       // 524288
    const size_t reserve    = (sums_elems + w5se_elems) * sizeof(float); // ~2.03 MB
    const size_t per_batch  = (size_t)CEXP * HWP * sizeof(float);        // ~12.85 MB

    float* sums = (float*)d_ws;
    float* w5se = sums + sums_elems;
    float* h2   = w5se + w5se_elems;

    const size_t avail = (ws_size > reserve) ? (ws_size - reserve) : 0;
    const int fit = (int)((avail / per_batch) > 32 ? 32 : (avail / per_batch));
    // choose batch-chunk size nb (divisor of 32); nb==0 -> tier B
    int nb = 0;
    if (fit >= 32) nb = 32;
    else if (fit >= 16) nb = 16;
    else if (fit >= 8) nb = 8;

    hipMemsetAsync(sums, 0, sums_elems * sizeof(float), stream);

    if (nb > 0) {
        // ---- Tier A: store h2 (multi-pass if needed; stream order makes
        // buffer reuse across passes safe) ----
        const int npasses = BATCH / nb;
        for (int p = 0; p < npasses; ++p) {
            const int b0 = p * nb;
            k1_expand_dw<true><<<dim3(NTIL * NTIL, nb), 256, 0, stream>>>(
                x, w1, w2, b1, b2, h2, sums, b0);
            k2_se<<<dim3(nb), 256, 0, stream>>>(sums, w3, w4, w5, b3, b4, w5se, b0);
            k3_project<<<dim3(HWP / 256, nb), 256, 0, stream>>>(h2, w5se, b5, out, b0);
        }
    } else {
        // ---- Tier B: no h2; recompute expand+dw inside fused project ----
        k1_expand_dw<false><<<dim3(NTIL * NTIL, BATCH), 256, 0, stream>>>(
            x, w1, w2, b1, b2, nullptr, sums, 0);
        k2_se<<<dim3(BATCH), 256, 0, stream>>>(sums, w3, w4, w5, b3, b4, w5se, 0);
        k3_fused<<<dim3(NTIL * NTIL, BATCH), 256, 0, stream>>>(
            x, w1, w2, b1, b2, w5se, b5, out);
    }
}

// Round 9
// 1534.316 us; speedup vs baseline: 1.6453x; 1.6453x over previous
//
#include <hip/hip_runtime.h>
#include <cstdint>

// Problem constants
#define BATCH 32
#define CIN   64
#define CEXP  256
#define CSE   64
#define COUT  64
#define HH    112
#define WW    112
#define HWP   (112*112)   // 12544
#define TILE  14          // interior tile
#define THL   16          // tile + 3x3 halo = 256 halo pixels = 1/thread
#define NTIL  8           // 112/14
#define CHUNK 16          // expand-channel chunk
#define HPAD  17          // padded row stride (floats) for h1s -> breaks bank conflicts
#define HCH   (THL*HPAD)  // 272 floats per channel slab

// -------------------------------------------------------------------------
// Kernel 1: fused expand 1x1 + ReLU + depthwise 3x3 + bias + ReLU.
// STORE=1: writes h2 [nb][256][112][112] (local batch) + per-(b,ch) sums.
// Block = (local batch, 14x14 tile), 256 threads = one 16x16 halo pixel.
// All small tensors (w1 chunk / w2 / b1 / b2) staged in LDS -> wave-uniform
// broadcast reads (no SMEM latency chains). Channel sums: 8 interleaved
// butterfly trees -> LDS vsum -> 1 global atomic per thread per block.
// -------------------------------------------------------------------------
template <bool STORE>
__global__ __launch_bounds__(256) void k1_expand_dw(
    const float* __restrict__ x, const float* __restrict__ w1,
    const float* __restrict__ w2, const float* __restrict__ b1,
    const float* __restrict__ b2, float* __restrict__ h2,
    float* __restrict__ sums, int b0)
{
    __shared__ __align__(16) float h1s[CHUNK][HCH];        // 17408 B
    __shared__ __align__(16) float wstage[2][CHUNK][CIN];  //  8192 B
    __shared__ __align__(16) float w2s[CEXP * 9];          //  9216 B
    __shared__ float bs1[CEXP], bs2[CEXP];                 //  2048 B
    __shared__ float vsum[CEXP];                           //  1024 B
    // total 37.9 KB -> 4 blocks/CU

    const int tid = threadIdx.x;
    const int bl  = blockIdx.y;          // local batch (h2 index)
    const int bg  = b0 + bl;             // global batch (x / sums index)
    const int tile = blockIdx.x;
    const int ty = tile >> 3, tx = tile & 7;
    const int h0 = ty * TILE - 1, w0 = tx * TILE - 1;

    // ---- one-time LDS staging of small tensors ----
    ((float4*)&wstage[0][0][0])[tid] = *(const float4*)(w1 + tid * 4); // chunk 0
    for (int i = tid; i < CEXP * 9; i += 256) w2s[i] = w2[i];
    bs1[tid] = b1[tid];
    bs2[tid] = b2[tid];
    vsum[tid] = 0.f;

    // ---- per-thread x pixel (all 64 input channels in registers) ----
    const int hy = tid >> 4, hx = tid & 15;
    const int hh = h0 + hy, ww = w0 + hx;
    const bool in = ((unsigned)hh < HH) && ((unsigned)ww < WW);
    float xr[CIN];
    {
        const float* xb = x + (size_t)bg * CIN * HWP;
        const int off = in ? (hh * WW + ww) : 0;
        #pragma unroll
        for (int c = 0; c < CIN; ++c) xr[c] = xb[c * HWP + off];
        if (!in) {
            #pragma unroll
            for (int c = 0; c < CIN; ++c) xr[c] = 0.f;
        }
    }

    const bool active = (tid < TILE * TILE);
    const int  y_  = tid / TILE;
    const int  y   = active ? y_ : 0;
    const int  xc  = active ? (tid - y_ * TILE) : 0;
    const int  lane = tid & 63;
    const size_t h2base = (size_t)bl * CEXP * HWP;

    __syncthreads();

    for (int chunk = 0; chunk < CEXP / CHUNK; ++chunk) {
        const int buf = chunk & 1;
        const int oc0 = chunk * CHUNK;

        // ---- expand: weights via LDS broadcast, dual FMA chains ----
        #pragma unroll 2
        for (int ocb = 0; ocb < CHUNK; ++ocb) {
            const float* __restrict__ wr = &wstage[buf][ocb][0];
            float a0 = bs1[oc0 + ocb], a1 = 0.f;
            #pragma unroll
            for (int c4 = 0; c4 < CIN / 4; ++c4) {
                const float4 w4 = *(const float4*)&wr[c4 * 4]; // uniform -> broadcast
                a0 = fmaf(xr[c4 * 4 + 0], w4.x, a0);
                a1 = fmaf(xr[c4 * 4 + 1], w4.y, a1);
                a0 = fmaf(xr[c4 * 4 + 2], w4.z, a0);
                a1 = fmaf(xr[c4 * 4 + 3], w4.w, a1);
            }
            h1s[ocb][hy * HPAD + hx] = in ? fmaxf(a0 + a1, 0.f) : 0.f;
        }
        __syncthreads();

        // prefetch next chunk's w1 rows (latency hidden under dw phase)
        float4 wpf;
        const bool havepf = (chunk + 1 < CEXP / CHUNK);
        if (havepf)
            wpf = *(const float4*)(w1 + (chunk + 1) * CHUNK * CIN + tid * 4);

        // ---- depthwise 3x3 + ReLU + store, 8 interleaved reduce trees ----
        #pragma unroll
        for (int g = 0; g < 2; ++g) {
            float v[8];
            #pragma unroll
            for (int r = 0; r < 8; ++r) {
                const int i  = g * 8 + r;
                const int oc = oc0 + i;
                float vv = bs2[oc];
                #pragma unroll
                for (int ky = 0; ky < 3; ++ky)
                    #pragma unroll
                    for (int kx = 0; kx < 3; ++kx)
                        vv = fmaf(h1s[i][(y + ky) * HPAD + (xc + kx)],
                                  w2s[oc * 9 + ky * 3 + kx], vv);
                vv = fmaxf(vv, 0.f);
                vv = active ? vv : 0.f;
                if (STORE && active)
                    h2[h2base + (size_t)oc * HWP +
                       (ty * TILE + y) * WW + (tx * TILE + xc)] = vv;
                v[r] = vv;
            }
            // 8 independent butterfly trees, stages interleaved (hides latency)
            #pragma unroll
            for (int st = 1; st < 64; st <<= 1) {
                #pragma unroll
                for (int r = 0; r < 8; ++r)
                    v[r] += __shfl_xor(v[r], st, 64);
            }
            #pragma unroll
            for (int r = 0; r < 8; ++r)
                if (lane == r) atomicAdd(&vsum[oc0 + g * 8 + r], v[r]);
        }

        if (havepf) ((float4*)&wstage[buf ^ 1][0][0])[tid] = wpf;
        __syncthreads();
    }

    // one global atomic per thread per block
    atomicAdd(&sums[bg * CEXP + tid], vsum[tid]);
}

// -------------------------------------------------------------------------
// Kernel 2: SE tail. mean -> FC(64)+ReLU -> FC(256)+sigmoid, pre-fold into
// w5se[b][e][o] = w5[o][e] * se2[b][e]. One block per batch in [b0, b0+nb).
// -------------------------------------------------------------------------
__global__ __launch_bounds__(256) void k2_se(
    const float* __restrict__ sums, const float* __restrict__ w3,
    const float* __restrict__ w4, const float* __restrict__ w5,
    const float* __restrict__ b3, const float* __restrict__ b4,
    float* __restrict__ w5se, int b0)
{
    __shared__ float mean_s[CEXP];
    __shared__ float se1_s[CSE];
    __shared__ float se2_s[CEXP];

    const int tid = threadIdx.x;
    const int b   = b0 + blockIdx.x;

    mean_s[tid] = sums[b * CEXP + tid] * (1.f / (float)HWP);
    __syncthreads();

    if (tid < CSE) {
        float a0 = b3[tid], a1 = 0.f;
        for (int e = 0; e < CEXP; e += 2) {
            a0 = fmaf(mean_s[e],     w3[tid * CEXP + e],     a0);
            a1 = fmaf(mean_s[e + 1], w3[tid * CEXP + e + 1], a1);
        }
        se1_s[tid] = fmaxf(a0 + a1, 0.f);
    }
    __syncthreads();

    {
        float a0 = b4[tid], a1 = 0.f;
        #pragma unroll
        for (int s = 0; s < CSE; s += 2) {
            a0 = fmaf(se1_s[s],     w4[tid * CSE + s],     a0);
            a1 = fmaf(se1_s[s + 1], w4[tid * CSE + s + 1], a1);
        }
        se2_s[tid] = 1.f / (1.f + expf(-(a0 + a1)));
    }
    __syncthreads();

    for (int i = tid; i < CEXP * COUT; i += 256) {
        const int e = i >> 6, o = i & 63;
        w5se[(size_t)b * CEXP * COUT + i] = w5[o * CEXP + e] * se2_s[e];
    }
}

// -------------------------------------------------------------------------
// Kernel 3 (tier A): project 1x1 as an LDS-staged fp32 GEMM.
// out[64,12544] = w5se_b[·,64]^T · h2_b[256,12544] per batch.
// Block = (pixel tile of 256, local batch). K staged in chunks of 32:
// h2 tile 32x256 (32 KB, coalesced float4, 8 outstanding loads/thread) +
// weights 32x64 (8 KB). Inner loop: 1 ds_read + 64 FMA per e.
// -------------------------------------------------------------------------
#define KC 32
__global__ __launch_bounds__(256) void k3_project(
    const float* __restrict__ h2, const float* __restrict__ w5se,
    const float* __restrict__ b5, float* __restrict__ out, int b0)
{
    __shared__ __align__(16) float hs[KC][256];    // 32 KB
    __shared__ __align__(16) float ws[KC][COUT];   //  8 KB

    const int tid = threadIdx.x;
    const int bl  = blockIdx.y;
    const int bg  = b0 + bl;
    const int p0  = blockIdx.x * 256;

    const float* __restrict__ hb = h2 + (size_t)bl * CEXP * HWP + p0;
    const float* __restrict__ wb = w5se + (size_t)bg * CEXP * COUT;

    float acc[COUT];
    #pragma unroll
    for (int o = 0; o < COUT; ++o) acc[o] = b5[o];

    for (int e0 = 0; e0 < CEXP; e0 += KC) {
        // stage h2 chunk: 2048 float4, 8 per thread, fully coalesced
        #pragma unroll
        for (int i = 0; i < 8; ++i) {
            const int f4 = i * 256 + tid;
            const int r  = f4 >> 6, c4 = f4 & 63;
            ((float4*)&hs[0][0])[f4] =
                *(const float4*)(hb + (size_t)(e0 + r) * HWP + c4 * 4);
        }
        // stage weight chunk: 512 float4, 2 per thread
        #pragma unroll
        for (int i = 0; i < 2; ++i)
            ((float4*)&ws[0][0])[i * 256 + tid] =
                ((const float4*)(wb + e0 * COUT))[i * 256 + tid];
        __syncthreads();

        for (int e = 0; e < KC; ++e) {
            const float hv = hs[e][tid];                 // stride-1: conflict-free
            #pragma unroll
            for (int o4 = 0; o4 < COUT / 4; ++o4) {
                const float4 w4 = *(const float4*)&ws[e][o4 * 4]; // broadcast
                acc[o4 * 4 + 0] = fmaf(hv, w4.x, acc[o4 * 4 + 0]);
                acc[o4 * 4 + 1] = fmaf(hv, w4.y, acc[o4 * 4 + 1]);
                acc[o4 * 4 + 2] = fmaf(hv, w4.z, acc[o4 * 4 + 2]);
                acc[o4 * 4 + 3] = fmaf(hv, w4.w, acc[o4 * 4 + 3]);
            }
        }
        __syncthreads();
    }

    float* __restrict__ op = out + (size_t)bg * COUT * HWP + p0 + tid;
    #pragma unroll
    for (int o = 0; o < COUT; ++o) op[(size_t)o * HWP] = acc[o];
}

// -------------------------------------------------------------------------
// Kernel 3 (tier B fallback, ws too small for h2): recompute expand+dw per
// tile and project in registers. (Unused when ws >= ~105 MB; kept correct.)
// -------------------------------------------------------------------------
__global__ __launch_bounds__(256) void k3_fused(
    const float* __restrict__ x, const float* __restrict__ w1,
    const float* __restrict__ w2, const float* __restrict__ b1,
    const float* __restrict__ b2, const float* __restrict__ w5se,
    const float* __restrict__ b5, float* __restrict__ out)
{
    __shared__ __align__(16) float h1s[CHUNK][HCH];

    const int tid = threadIdx.x;
    const int b   = blockIdx.y;
    const int tile = blockIdx.x;
    const int ty = tile >> 3, tx = tile & 7;
    const int h0 = ty * TILE - 1, w0 = tx * TILE - 1;

    const int hy = tid >> 4, hx = tid & 15;
    const int hh = h0 + hy, ww = w0 + hx;
    const bool in = ((unsigned)hh < HH) && ((unsigned)ww < WW);

    float xr[CIN];
    {
        const float* xb = x + (size_t)b * CIN * HWP;
        const int off = in ? (hh * WW + ww) : 0;
        #pragma unroll
        for (int c = 0; c < CIN; ++c) xr[c] = xb[c * HWP + off];
        if (!in) {
            #pragma unroll
            for (int c = 0; c < CIN; ++c) xr[c] = 0.f;
        }
    }

    const bool active = (tid < TILE * TILE);
    const int  y_  = tid / TILE;
    const int  y   = active ? y_ : 0;
    const int  xc  = active ? (tid - y_ * TILE) : 0;

    const float* __restrict__ wp = w5se + (size_t)b * CEXP * COUT;

    float acc[COUT];
    #pragma unroll
    for (int o = 0; o < COUT; ++o) acc[o] = b5[o];

    for (int chunk = 0; chunk < CEXP / CHUNK; ++chunk) {
        const int oc0 = chunk * CHUNK;

        #pragma unroll 2
        for (int ocb = 0; ocb < CHUNK; ++ocb) {
            const int oc = oc0 + ocb;
            const float* __restrict__ wr = w1 + oc * CIN;
            float a0 = b1[oc], a1 = 0.f;
            #pragma unroll
            for (int c = 0; c < CIN; c += 2) {
                a0 = fmaf(xr[c],     wr[c],     a0);
                a1 = fmaf(xr[c + 1], wr[c + 1], a1);
            }
            h1s[ocb][hy * HPAD + hx] = in ? fmaxf(a0 + a1, 0.f) : 0.f;
        }
        __syncthreads();

        for (int i = 0; i < CHUNK; ++i) {
            const int oc = oc0 + i;
            const float* __restrict__ w2r = w2 + oc * 9;
            float v = b2[oc];
            #pragma unroll
            for (int ky = 0; ky < 3; ++ky)
                #pragma unroll
                for (int kx = 0; kx < 3; ++kx)
                    v = fmaf(h1s[i][(y + ky) * HPAD + (xc + kx)], w2r[ky * 3 + kx], v);
            v = fmaxf(v, 0.f);
            const float* __restrict__ wr = wp + oc * COUT;
            #pragma unroll
            for (int o = 0; o < COUT; ++o)
                acc[o] = fmaf(v, wr[o], acc[o]);
        }
        __syncthreads();
    }

    if (active) {
        const int p = (ty * TILE + y) * WW + (tx * TILE + xc);
        float* __restrict__ op = out + (size_t)b * COUT * HWP + p;
        #pragma unroll
        for (int o = 0; o < COUT; ++o) op[(size_t)o * HWP] = acc[o];
    }
}

// -------------------------------------------------------------------------
extern "C" void kernel_launch(void* const* d_in, const int* in_sizes, int n_in,
                              void* d_out, int out_size, void* d_ws, size_t ws_size,
                              hipStream_t stream)
{
    const float* x  = (const float*)d_in[0];
    const float* w1 = (const float*)d_in[1];
    const float* w2 = (const float*)d_in[2];
    const float* w3 = (const float*)d_in[3];
    const float* w4 = (const float*)d_in[4];
    const float* w5 = (const float*)d_in[5];
    const float* b1 = (const float*)d_in[6];
    const float* b2 = (const float*)d_in[7];
    const float* b3 = (const float*)d_in[8];
    const float* b4 = (const float*)d_in[9];
    const float* b5 = (const float*)d_in[10];
    float* out = (float*)d_out;

    // workspace layout: sums (32 KB) | w5se (2 MB) | h2 (whatever fits)
    const size_t sums_elems = (size_t)BATCH * CEXP;
    const size_t w5se_elems = (size_t)BATCH * CEXP * COUT;
    const size_t reserve    = (sums_elems + w5se_elems) * sizeof(float);
    const size_t per_batch  = (size_t)CEXP * HWP * sizeof(float);

    float* sums = (float*)d_ws;
    float* w5se = sums + sums_elems;
    float* h2   = w5se + w5se_elems;

    const size_t avail = (ws_size > reserve) ? (ws_size - reserve) : 0;
    const int fit = (int)((avail / per_batch) > 32 ? 32 : (avail / per_batch));
    int nb = 0;
    if (fit >= 32) nb = 32;
    else if (fit >= 16) nb = 16;
    else if (fit >= 8) nb = 8;

    hipMemsetAsync(sums, 0, sums_elems * sizeof(float), stream);

    if (nb > 0) {
        const int npasses = BATCH / nb;
        for (int p = 0; p < npasses; ++p) {
            const int b0 = p * nb;
            k1_expand_dw<true><<<dim3(NTIL * NTIL, nb), 256, 0, stream>>>(
                x, w1, w2, b1, b2, h2, sums, b0);
            k2_se<<<dim3(nb), 256, 0, stream>>>(sums, w3, w4, w5, b3, b4, w5se, b0);
            k3_project<<<dim3(HWP / 256, nb), 256, 0, stream>>>(h2, w5se, b5, out, b0);
        }
    } else {
        k1_expand_dw<false><<<dim3(NTIL * NTIL, BATCH), 256, 0, stream>>>(
            x, w1, w2, b1, b2, nullptr, sums, 0);
        k2_se<<<dim3(BATCH), 256, 0, stream>>>(sums, w3, w4, w5, b3, b4, w5se, 0);
        k3_fused<<<dim3(NTIL * NTIL, BATCH), 256, 0, stream>>>(
            x, w1, w2, b1, b2, w5se, b5, out);
    }
}

// Round 10
// 1128.458 us; speedup vs baseline: 2.2371x; 1.3597x over previous
//
#include <hip/hip_runtime.h>
#include <cstdint>

// Problem constants
#define BATCH 32
#define CIN   64
#define CEXP  256
#define CSE   64
#define COUT  64
#define HH    112
#define WW    112
#define HWP   (112*112)   // 12544
#define TILE  14          // interior tile
#define THL   16          // tile + 3x3 halo = 256 halo pixels = 1/thread
#define NTIL  8           // 112/14
#define CHUNK 16          // expand-channel chunk
#define HPAD  17          // padded row stride (floats) for h1s
#define HCH   (THL*HPAD)  // 272 floats per channel slab

// -------------------------------------------------------------------------
// Kernel 1: fused expand 1x1 + ReLU + depthwise 3x3 + bias + ReLU.
// UNCHANGED from round 9 (measured 444 us) — one-variable discipline.
// -------------------------------------------------------------------------
template <bool STORE>
__global__ __launch_bounds__(256) void k1_expand_dw(
    const float* __restrict__ x, const float* __restrict__ w1,
    const float* __restrict__ w2, const float* __restrict__ b1,
    const float* __restrict__ b2, float* __restrict__ h2,
    float* __restrict__ sums, int b0)
{
    __shared__ __align__(16) float h1s[CHUNK][HCH];        // 17408 B
    __shared__ __align__(16) float wstage[2][CHUNK][CIN];  //  8192 B
    __shared__ __align__(16) float w2s[CEXP * 9];          //  9216 B
    __shared__ float bs1[CEXP], bs2[CEXP];                 //  2048 B
    __shared__ float vsum[CEXP];                           //  1024 B

    const int tid = threadIdx.x;
    const int bl  = blockIdx.y;          // local batch (h2 index)
    const int bg  = b0 + bl;             // global batch (x / sums index)
    const int tile = blockIdx.x;
    const int ty = tile >> 3, tx = tile & 7;
    const int h0 = ty * TILE - 1, w0 = tx * TILE - 1;

    // ---- one-time LDS staging of small tensors ----
    ((float4*)&wstage[0][0][0])[tid] = *(const float4*)(w1 + tid * 4); // chunk 0
    for (int i = tid; i < CEXP * 9; i += 256) w2s[i] = w2[i];
    bs1[tid] = b1[tid];
    bs2[tid] = b2[tid];
    vsum[tid] = 0.f;

    // ---- per-thread x pixel (all 64 input channels in registers) ----
    const int hy = tid >> 4, hx = tid & 15;
    const int hh = h0 + hy, ww = w0 + hx;
    const bool in = ((unsigned)hh < HH) && ((unsigned)ww < WW);
    float xr[CIN];
    {
        const float* xb = x + (size_t)bg * CIN * HWP;
        const int off = in ? (hh * WW + ww) : 0;
        #pragma unroll
        for (int c = 0; c < CIN; ++c) xr[c] = xb[c * HWP + off];
        if (!in) {
            #pragma unroll
            for (int c = 0; c < CIN; ++c) xr[c] = 0.f;
        }
    }

    const bool active = (tid < TILE * TILE);
    const int  y_  = tid / TILE;
    const int  y   = active ? y_ : 0;
    const int  xc  = active ? (tid - y_ * TILE) : 0;
    const int  lane = tid & 63;
    const size_t h2base = (size_t)bl * CEXP * HWP;

    __syncthreads();

    for (int chunk = 0; chunk < CEXP / CHUNK; ++chunk) {
        const int buf = chunk & 1;
        const int oc0 = chunk * CHUNK;

        // ---- expand: weights via LDS broadcast, dual FMA chains ----
        #pragma unroll 2
        for (int ocb = 0; ocb < CHUNK; ++ocb) {
            const float* __restrict__ wr = &wstage[buf][ocb][0];
            float a0 = bs1[oc0 + ocb], a1 = 0.f;
            #pragma unroll
            for (int c4 = 0; c4 < CIN / 4; ++c4) {
                const float4 w4 = *(const float4*)&wr[c4 * 4]; // uniform -> broadcast
                a0 = fmaf(xr[c4 * 4 + 0], w4.x, a0);
                a1 = fmaf(xr[c4 * 4 + 1], w4.y, a1);
                a0 = fmaf(xr[c4 * 4 + 2], w4.z, a0);
                a1 = fmaf(xr[c4 * 4 + 3], w4.w, a1);
            }
            h1s[ocb][hy * HPAD + hx] = in ? fmaxf(a0 + a1, 0.f) : 0.f;
        }
        __syncthreads();

        // prefetch next chunk's w1 rows (latency hidden under dw phase)
        float4 wpf;
        const bool havepf = (chunk + 1 < CEXP / CHUNK);
        if (havepf)
            wpf = *(const float4*)(w1 + (chunk + 1) * CHUNK * CIN + tid * 4);

        // ---- depthwise 3x3 + ReLU + store, 8 interleaved reduce trees ----
        #pragma unroll
        for (int g = 0; g < 2; ++g) {
            float v[8];
            #pragma unroll
            for (int r = 0; r < 8; ++r) {
                const int i  = g * 8 + r;
                const int oc = oc0 + i;
                float vv = bs2[oc];
                #pragma unroll
                for (int ky = 0; ky < 3; ++ky)
                    #pragma unroll
                    for (int kx = 0; kx < 3; ++kx)
                        vv = fmaf(h1s[i][(y + ky) * HPAD + (xc + kx)],
                                  w2s[oc * 9 + ky * 3 + kx], vv);
                vv = fmaxf(vv, 0.f);
                vv = active ? vv : 0.f;
                if (STORE && active)
                    h2[h2base + (size_t)oc * HWP +
                       (ty * TILE + y) * WW + (tx * TILE + xc)] = vv;
                v[r] = vv;
            }
            #pragma unroll
            for (int st = 1; st < 64; st <<= 1) {
                #pragma unroll
                for (int r = 0; r < 8; ++r)
                    v[r] += __shfl_xor(v[r], st, 64);
            }
            #pragma unroll
            for (int r = 0; r < 8; ++r)
                if (lane == r) atomicAdd(&vsum[oc0 + g * 8 + r], v[r]);
        }

        if (havepf) ((float4*)&wstage[buf ^ 1][0][0])[tid] = wpf;
        __syncthreads();
    }

    atomicAdd(&sums[bg * CEXP + tid], vsum[tid]);
}

// -------------------------------------------------------------------------
// Kernel 2: SE tail (unchanged).
// -------------------------------------------------------------------------
__global__ __launch_bounds__(256) void k2_se(
    const float* __restrict__ sums, const float* __restrict__ w3,
    const float* __restrict__ w4, const float* __restrict__ w5,
    const float* __restrict__ b3, const float* __restrict__ b4,
    float* __restrict__ w5se, int b0)
{
    __shared__ float mean_s[CEXP];
    __shared__ float se1_s[CSE];
    __shared__ float se2_s[CEXP];

    const int tid = threadIdx.x;
    const int b   = b0 + blockIdx.x;

    mean_s[tid] = sums[b * CEXP + tid] * (1.f / (float)HWP);
    __syncthreads();

    if (tid < CSE) {
        float a0 = b3[tid], a1 = 0.f;
        for (int e = 0; e < CEXP; e += 2) {
            a0 = fmaf(mean_s[e],     w3[tid * CEXP + e],     a0);
            a1 = fmaf(mean_s[e + 1], w3[tid * CEXP + e + 1], a1);
        }
        se1_s[tid] = fmaxf(a0 + a1, 0.f);
    }
    __syncthreads();

    {
        float a0 = b4[tid], a1 = 0.f;
        #pragma unroll
        for (int s = 0; s < CSE; s += 2) {
            a0 = fmaf(se1_s[s],     w4[tid * CSE + s],     a0);
            a1 = fmaf(se1_s[s + 1], w4[tid * CSE + s + 1], a1);
        }
        se2_s[tid] = 1.f / (1.f + expf(-(a0 + a1)));
    }
    __syncthreads();

    for (int i = tid; i < CEXP * COUT; i += 256) {
        const int e = i >> 6, o = i & 63;
        w5se[(size_t)b * CEXP * COUT + i] = w5[o * CEXP + e] * se2_s[e];
    }
}

// -------------------------------------------------------------------------
// Kernel 3 (tier A), v2: 8x8 REGISTER-TILED fp32 GEMM.
// Block tile: 64 outputs x 256 pixels. Thread (oc=tid&7, pr=tid>>3) computes
// an 8-output x 8-pixel micro-tile. Per e: 2+2 ds_read_b128 (8px + 8w, both
// 8-lane-broadcast, 2-way bank alias = free) feed 64 FMAs -> VALU-bound.
// Replaces v1's 17 LDS instr/e (6x LDS-oversubscribed, ~980 us measured).
// -------------------------------------------------------------------------
#define KC 32
__global__ __launch_bounds__(256) void k3_project(
    const float* __restrict__ h2, const float* __restrict__ w5se,
    const float* __restrict__ b5, float* __restrict__ out, int b0)
{
    __shared__ __align__(16) float hs[KC][256];    // 32 KB
    __shared__ __align__(16) float ws[KC][COUT];   //  8 KB

    const int tid = threadIdx.x;
    const int bl  = blockIdx.y;
    const int bg  = b0 + bl;
    const int p0  = blockIdx.x * 256;

    const int oc = tid & 7;    // output group: channels oc*8 .. oc*8+7
    const int pr = tid >> 3;   // pixel group:  pixels  pr*8 .. pr*8+7

    const float* __restrict__ hb = h2 + (size_t)bl * CEXP * HWP + p0;
    const float* __restrict__ wb = w5se + (size_t)bg * CEXP * COUT;

    float acc[8][8];
    #pragma unroll
    for (int j = 0; j < 8; ++j) {
        const float bv = b5[oc * 8 + j];
        #pragma unroll
        for (int i = 0; i < 8; ++i) acc[j][i] = bv;
    }

    for (int e0 = 0; e0 < CEXP; e0 += KC) {
        // stage h2 chunk: 2048 float4, 8 per thread, fully coalesced
        #pragma unroll
        for (int i = 0; i < 8; ++i) {
            const int f4 = i * 256 + tid;
            const int r  = f4 >> 6, c4 = f4 & 63;
            ((float4*)&hs[0][0])[f4] =
                *(const float4*)(hb + (size_t)(e0 + r) * HWP + c4 * 4);
        }
        // stage weight chunk: 512 float4, 2 per thread
        #pragma unroll
        for (int i = 0; i < 2; ++i)
            ((float4*)&ws[0][0])[i * 256 + tid] =
                ((const float4*)(wb + e0 * COUT))[i * 256 + tid];
        __syncthreads();

        #pragma unroll 4
        for (int e = 0; e < KC; ++e) {
            const float4 h0 = *(const float4*)&hs[e][pr * 8];
            const float4 h1 = *(const float4*)&hs[e][pr * 8 + 4];
            const float4 w0 = *(const float4*)&ws[e][oc * 8];
            const float4 w1 = *(const float4*)&ws[e][oc * 8 + 4];
            const float hv[8] = {h0.x, h0.y, h0.z, h0.w, h1.x, h1.y, h1.z, h1.w};
            const float wv[8] = {w0.x, w0.y, w0.z, w0.w, w1.x, w1.y, w1.z, w1.w};
            #pragma unroll
            for (int j = 0; j < 8; ++j)
                #pragma unroll
                for (int i = 0; i < 8; ++i)
                    acc[j][i] = fmaf(wv[j], hv[i], acc[j][i]);
        }
        __syncthreads();
    }

    // epilogue: 8 outputs x 8 consecutive pixels per thread (2 float4 / row)
    #pragma unroll
    for (int j = 0; j < 8; ++j) {
        float* __restrict__ op = out + (size_t)bg * COUT * HWP
                               + (size_t)(oc * 8 + j) * HWP + p0 + pr * 8;
        *(float4*)op       = make_float4(acc[j][0], acc[j][1], acc[j][2], acc[j][3]);
        *((float4*)op + 1) = make_float4(acc[j][4], acc[j][5], acc[j][6], acc[j][7]);
    }
}

// -------------------------------------------------------------------------
// Kernel 3 (tier B fallback, unchanged; unused when ws fits h2).
// -------------------------------------------------------------------------
__global__ __launch_bounds__(256) void k3_fused(
    const float* __restrict__ x, const float* __restrict__ w1,
    const float* __restrict__ w2, const float* __restrict__ b1,
    const float* __restrict__ b2, const float* __restrict__ w5se,
    const float* __restrict__ b5, float* __restrict__ out)
{
    __shared__ __align__(16) float h1s[CHUNK][HCH];

    const int tid = threadIdx.x;
    const int b   = blockIdx.y;
    const int tile = blockIdx.x;
    const int ty = tile >> 3, tx = tile & 7;
    const int h0 = ty * TILE - 1, w0 = tx * TILE - 1;

    const int hy = tid >> 4, hx = tid & 15;
    const int hh = h0 + hy, ww = w0 + hx;
    const bool in = ((unsigned)hh < HH) && ((unsigned)ww < WW);

    float xr[CIN];
    {
        const float* xb = x + (size_t)b * CIN * HWP;
        const int off = in ? (hh * WW + ww) : 0;
        #pragma unroll
        for (int c = 0; c < CIN; ++c) xr[c] = xb[c * HWP + off];
        if (!in) {
            #pragma unroll
            for (int c = 0; c < CIN; ++c) xr[c] = 0.f;
        }
    }

    const bool active = (tid < TILE * TILE);
    const int  y_  = tid / TILE;
    const int  y   = active ? y_ : 0;
    const int  xc  = active ? (tid - y_ * TILE) : 0;

    const float* __restrict__ wp = w5se + (size_t)b * CEXP * COUT;

    float acc[COUT];
    #pragma unroll
    for (int o = 0; o < COUT; ++o) acc[o] = b5[o];

    for (int chunk = 0; chunk < CEXP / CHUNK; ++chunk) {
        const int oc0 = chunk * CHUNK;

        #pragma unroll 2
        for (int ocb = 0; ocb < CHUNK; ++ocb) {
            const int oc = oc0 + ocb;
            const float* __restrict__ wr = w1 + oc * CIN;
            float a0 = b1[oc], a1 = 0.f;
            #pragma unroll
            for (int c = 0; c < CIN; c += 2) {
                a0 = fmaf(xr[c],     wr[c],     a0);
                a1 = fmaf(xr[c + 1], wr[c + 1], a1);
            }
            h1s[ocb][hy * HPAD + hx] = in ? fmaxf(a0 + a1, 0.f) : 0.f;
        }
        __syncthreads();

        for (int i = 0; i < CHUNK; ++i) {
            const int oc = oc0 + i;
            const float* __restrict__ w2r = w2 + oc * 9;
            float v = b2[oc];
            #pragma unroll
            for (int ky = 0; ky < 3; ++ky)
                #pragma unroll
                for (int kx = 0; kx < 3; ++kx)
                    v = fmaf(h1s[i][(y + ky) * HPAD + (xc + kx)], w2r[ky * 3 + kx], v);
            v = fmaxf(v, 0.f);
            const float* __restrict__ wr = wp + oc * COUT;
            #pragma unroll
            for (int o = 0; o < COUT; ++o)
                acc[o] = fmaf(v, wr[o], acc[o]);
        }
        __syncthreads();
    }

    if (active) {
        const int p = (ty * TILE + y) * WW + (tx * TILE + xc);
        float* __restrict__ op = out + (size_t)b * COUT * HWP + p;
        #pragma unroll
        for (int o = 0; o < COUT; ++o) op[(size_t)o * HWP] = acc[o];
    }
}

// -------------------------------------------------------------------------
extern "C" void kernel_launch(void* const* d_in, const int* in_sizes, int n_in,
                              void* d_out, int out_size, void* d_ws, size_t ws_size,
                              hipStream_t stream)
{
    const float* x  = (const float*)d_in[0];
    const float* w1 = (const float*)d_in[1];
    const float* w2 = (const float*)d_in[2];
    const float* w3 = (const float*)d_in[3];
    const float* w4 = (const float*)d_in[4];
    const float* w5 = (const float*)d_in[5];
    const float* b1 = (const float*)d_in[6];
    const float* b2 = (const float*)d_in[7];
    const float* b3 = (const float*)d_in[8];
    const float* b4 = (const float*)d_in[9];
    const float* b5 = (const float*)d_in[10];
    float* out = (float*)d_out;

    // workspace layout: sums (32 KB) | w5se (2 MB) | h2 (whatever fits)
    const size_t sums_elems = (size_t)BATCH * CEXP;
    const size_t w5se_elems = (size_t)BATCH * CEXP * COUT;
    const size_t reserve    = (sums_elems + w5se_elems) * sizeof(float);
    const size_t per_batch  = (size_t)CEXP * HWP * sizeof(float);

    float* sums = (float*)d_ws;
    float* w5se = sums + sums_elems;
    float* h2   = w5se + w5se_elems;

    const size_t avail = (ws_size > reserve) ? (ws_size - reserve) : 0;
    const int fit = (int)((avail / per_batch) > 32 ? 32 : (avail / per_batch));
    int nb = 0;
    if (fit >= 32) nb = 32;
    else if (fit >= 16) nb = 16;
    else if (fit >= 8) nb = 8;

    hipMemsetAsync(sums, 0, sums_elems * sizeof(float), stream);

    if (nb > 0) {
        const int npasses = BATCH / nb;
        for (int p = 0; p < npasses; ++p) {
            const int b0 = p * nb;
            k1_expand_dw<true><<<dim3(NTIL * NTIL, nb), 256, 0, stream>>>(
                x, w1, w2, b1, b2, h2, sums, b0);
            k2_se<<<dim3(nb), 256, 0, stream>>>(sums, w3, w4, w5, b3, b4, w5se, b0);
            k3_project<<<dim3(HWP / 256, nb), 256, 0, stream>>>(h2, w5se, b5, out, b0);
        }
    } else {
        k1_expand_dw<false><<<dim3(NTIL * NTIL, BATCH), 256, 0, stream>>>(
            x, w1, w2, b1, b2, nullptr, sums, 0);
        k2_se<<<dim3(BATCH), 256, 0, stream>>>(sums, w3, w4, w5, b3, b4, w5se, 0);
        k3_fused<<<dim3(NTIL * NTIL, BATCH), 256, 0, stream>>>(
            x, w1, w2, b1, b2, w5se, b5, out);
    }
}